// Round 3
// baseline (93.577 us; speedup 1.0000x reference)
//
#include <hip/hip_runtime.h>
#include <math.h>

#define BZ 32
#define SRC_LEN 2048
#define DIM 1024
#define NCHUNK 64          // chunks per batch; chunk j owns rows s = j + 64*k
#define ROWS_PER_BLK 32    // SRC_LEN / NCHUNK, split over 4 waves (8 rows each)

// ---------------- kernel 1: proj[b][e] = sum_d tgt[b][d] * Wg[e][d] ----------
// grid 128 blocks (e-chunks of 8), 256 threads. Wg read exactly once.
__global__ __launch_bounds__(256) void k_proj(const float* __restrict__ tgt,
                                              const float* __restrict__ Wg,
                                              float* __restrict__ proj) {
    __shared__ float tg[32 * 129];   // padded
    __shared__ float wt[8 * 128];
    const int t = threadIdx.x;
    const int e0 = blockIdx.x * 8;
    const int b = t & 31;
    const int eg = t >> 5;           // 0..7, owns 1 e
    float acc = 0.f;
    for (int d0 = 0; d0 < DIM; d0 += 128) {
        __syncthreads();
#pragma unroll
        for (int i = 0; i < 4; ++i) {
            int flat = t * 4 + i * 1024;
            int row = flat >> 7, col = flat & 127;
            float4 v = *(const float4*)&tgt[row * DIM + d0 + col];
            tg[row * 129 + col + 0] = v.x;
            tg[row * 129 + col + 1] = v.y;
            tg[row * 129 + col + 2] = v.z;
            tg[row * 129 + col + 3] = v.w;
        }
        {
            int flat = t * 4;
            int row = flat >> 7, col = flat & 127;
            *(float4*)&wt[flat] = *(const float4*)&Wg[(size_t)(e0 + row) * DIM + d0 + col];
        }
        __syncthreads();
        for (int kk = 0; kk < 128; ++kk)
            acc += tg[b * 129 + kk] * wt[eg * 128 + kk];
    }
    proj[b * DIM + e0 + eg] = acc;
}

// ---------------- kernel 2: flash pass, strided chunks, 4-row batches --------
// grid = 64 chunks * 32 b = 2048 blocks, 256 threads = 4 waves, 8 rows/wave.
__global__ __launch_bounds__(256) void k_flash(const float* __restrict__ src,
                                               const float* __restrict__ proj,
                                               const int* __restrict__ lens,
                                               float* __restrict__ scores,
                                               float* __restrict__ part_ml,
                                               float* __restrict__ part_c) {
    const int blk = blockIdx.x;
    const int b = blk & 31;          // interleave b so neighbor blocks differ
    const int j = blk >> 5;          // chunk id 0..63
    const int lane = threadIdx.x & 63;
    const int wave = threadIdx.x >> 6;
    const int len = lens[b];

    // live rows of this chunk: k in [0, nk), s = j + 64*k
    int nk = 0;
    if (len > j) nk = (len - j + 63) >> 6;

    float4 pj[4];
#pragma unroll
    for (int q = 0; q < 4; ++q)
        pj[q] = *(const float4*)&proj[b * DIM + (q * 64 + lane) * 4];

    const float* sb = src + (size_t)b * SRC_LEN * DIM;
    float m = -INFINITY, l = 0.f;
    float c[16];
#pragma unroll
    for (int i = 0; i < 16; ++i) c[i] = 0.f;

    const int kbeg = wave * 8;
    const int kend = (kbeg + 8 < nk) ? (kbeg + 8) : nk;

    for (int k0 = kbeg; k0 < kend; k0 += 4) {
        const int nb = ((kend - k0) < 4) ? (kend - k0) : 4;   // wave-uniform
        float4 v[4][4];
        float sc[4];
#pragma unroll
        for (int r = 0; r < 4; ++r) {
            if (r < nb) {
                const int s = j + 64 * (k0 + r);
                const float* row = sb + (size_t)s * DIM;
                float d = 0.f;
#pragma unroll
                for (int q = 0; q < 4; ++q) {
                    v[r][q] = *(const float4*)&row[(q * 64 + lane) * 4];
                    d += v[r][q].x * pj[q].x + v[r][q].y * pj[q].y +
                         v[r][q].z * pj[q].z + v[r][q].w * pj[q].w;
                }
                sc[r] = d;
            } else {
                sc[r] = -INFINITY;
            }
        }
        // 4 interleaved wave reductions (-inf rows stay -inf)
#pragma unroll
        for (int off = 32; off > 0; off >>= 1) {
            sc[0] += __shfl_xor(sc[0], off, 64);
            sc[1] += __shfl_xor(sc[1], off, 64);
            sc[2] += __shfl_xor(sc[2], off, 64);
            sc[3] += __shfl_xor(sc[3], off, 64);
        }
        if (lane == 0) {
#pragma unroll
            for (int r = 0; r < 4; ++r)
                if (r < nb) scores[b * SRC_LEN + j + 64 * (k0 + r)] = sc[r];
        }
        const float mn = fmaxf(m, fmaxf(fmaxf(sc[0], sc[1]), fmaxf(sc[2], sc[3])));
        const float scale = __expf(m - mn);  // m=-inf -> 0; mn finite here (nb>=1)
        float w[4];
#pragma unroll
        for (int r = 0; r < 4; ++r) w[r] = __expf(sc[r] - mn);  // dead -> 0
        l = l * scale + (w[0] + w[1] + w[2] + w[3]);
#pragma unroll
        for (int i = 0; i < 16; ++i) c[i] *= scale;
#pragma unroll
        for (int r = 0; r < 4; ++r) {
            if (r < nb) {   // guard: v[r] undefined when dead (NaN*0 hazard)
#pragma unroll
                for (int q = 0; q < 4; ++q) {
                    c[q * 4 + 0] += w[r] * v[r][q].x;
                    c[q * 4 + 1] += w[r] * v[r][q].y;
                    c[q * 4 + 2] += w[r] * v[r][q].z;
                    c[q * 4 + 3] += w[r] * v[r][q].w;
                }
            }
        }
        m = mn;
    }

    // combine the block's 4 waves
    __shared__ float s_c[4][1024];
    __shared__ float s_ml[4][2];
#pragma unroll
    for (int q = 0; q < 4; ++q)
        *(float4*)&s_c[wave][(q * 64 + lane) * 4] =
            make_float4(c[q * 4 + 0], c[q * 4 + 1], c[q * 4 + 2], c[q * 4 + 3]);
    if (lane == 0) { s_ml[wave][0] = m; s_ml[wave][1] = l; }
    __syncthreads();

    const int t = threadIdx.x;
    float M = fmaxf(fmaxf(s_ml[0][0], s_ml[1][0]), fmaxf(s_ml[2][0], s_ml[3][0]));
    float L = 0.f;
    float4 acc = make_float4(0.f, 0.f, 0.f, 0.f);
#pragma unroll
    for (int wv = 0; wv < 4; ++wv) {
        const float mw = s_ml[wv][0];
        const float e = (mw == -INFINITY) ? 0.f : __expf(mw - M);
        L += e * s_ml[wv][1];
        float4 cv = *(const float4*)&s_c[wv][t * 4];
        acc.x += e * cv.x; acc.y += e * cv.y; acc.z += e * cv.z; acc.w += e * cv.w;
    }
    if (t == 0) { part_ml[2 * blk] = M; part_ml[2 * blk + 1] = L; }
    if (M > -INFINITY)   // dead chunks: skip 4 KB write; merge skips the read
        *(float4*)&part_c[(size_t)blk * DIM + t * 4] = acc;
}

// ---------------- kernel 3: merge partials, write align, write c ------------
// grid 32 blocks (one per batch), 256 threads. part index = j*32 + b.
__global__ __launch_bounds__(256) void k_merge(const float* __restrict__ part_ml,
                                               const float* __restrict__ part_c,
                                               const float* __restrict__ scores,
                                               const int* __restrict__ lens,
                                               float* __restrict__ c_ws,
                                               float* __restrict__ out_align) {
    __shared__ float s_m[NCHUNK], s_l[NCHUNK];
    const int b = blockIdx.x;
    const int t = threadIdx.x;
    if (t < NCHUNK) {
        s_m[t] = part_ml[2 * (t * BZ + b)];
        s_l[t] = part_ml[2 * (t * BZ + b) + 1];
    }
    __syncthreads();
    float M = -INFINITY;
#pragma unroll
    for (int i = 0; i < NCHUNK; ++i) M = fmaxf(M, s_m[i]);
    float L = 0.f;
#pragma unroll
    for (int i = 0; i < NCHUNK; ++i) {
        if (s_m[i] > -INFINITY) L += __expf(s_m[i] - M) * s_l[i];
    }
    const float invL = 1.f / L;
    float4 acc = make_float4(0.f, 0.f, 0.f, 0.f);
    for (int i = 0; i < NCHUNK; ++i) {
        if (s_m[i] > -INFINITY) {   // uniform per block
            const float e = __expf(s_m[i] - M);
            float4 cv = *(const float4*)&part_c[(size_t)(i * BZ + b) * DIM + t * 4];
            acc.x += e * cv.x; acc.y += e * cv.y; acc.z += e * cv.z; acc.w += e * cv.w;
        }
    }
    acc.x *= invL; acc.y *= invL; acc.z *= invL; acc.w *= invL;
    *(float4*)&c_ws[b * DIM + t * 4] = acc;

    const int len = lens[b];
    for (int s = t; s < SRC_LEN; s += 256) {
        float a = 0.f;
        if (s < len) a = __expf(scores[b * SRC_LEN + s] - M) * invL;
        out_align[b * SRC_LEN + s] = a;
    }
}

// ---------------- kernel 4: attn_h = [c, tgt] @ Wo^T ------------------------
// grid 128 blocks (d-chunks of 8), 256 threads. Wo (8 MB) read exactly once.
__global__ __launch_bounds__(256) void k_out(const float* __restrict__ c_ws,
                                             const float* __restrict__ tgt,
                                             const float* __restrict__ Wo,
                                             float* __restrict__ out) {
    __shared__ float ct[32 * 257];  // padded
    __shared__ float wt[8 * 256];
    const int t = threadIdx.x;
    const int d0 = blockIdx.x * 8;
    const int b = t & 31;
    const int dg = t >> 5;          // 0..7, owns 1 d
    float acc = 0.f;
    for (int k0 = 0; k0 < 2 * DIM; k0 += 256) {
        __syncthreads();
        for (int i = 0; i < 32; ++i) {
            const int k = k0 + t;
            ct[i * 257 + t] = (k < DIM) ? c_ws[i * DIM + k] : tgt[i * DIM + (k - DIM)];
        }
#pragma unroll
        for (int i = 0; i < 8; ++i)
            wt[i * 256 + t] = Wo[(size_t)(d0 + i) * (2 * DIM) + k0 + t];
        __syncthreads();
        for (int kk = 0; kk < 256; ++kk)
            acc += ct[b * 257 + kk] * wt[dg * 256 + kk];
    }
    out[b * DIM + d0 + dg] = acc;
}

extern "C" void kernel_launch(void* const* d_in, const int* in_sizes, int n_in,
                              void* d_out, int out_size, void* d_ws, size_t ws_size,
                              hipStream_t stream) {
    const float* src = (const float*)d_in[0];   // (32, 2048, 1024)
    const float* tgt = (const float*)d_in[1];   // (32, 1, 1024)
    const float* Wg  = (const float*)d_in[2];   // (1024, 1024)
    const float* Wo  = (const float*)d_in[3];   // (1024, 2048)
    const int*   len = (const int*)d_in[4];     // (32,)
    float* out = (float*)d_out;                 // attn_h [0,32768) ++ align

    float* ws = (float*)d_ws;
    float* proj    = ws;                               // 32*1024
    float* scores  = proj + BZ * DIM;                  // 32*2048
    float* part_ml = scores + BZ * SRC_LEN;            // 2048*2
    float* part_c  = part_ml + BZ * NCHUNK * 2;        // 2048*1024 (8 MB)
    float* c_ws    = part_c + (size_t)BZ * NCHUNK * DIM;

    k_proj <<<DIM / 8,      256, 0, stream>>>(tgt, Wg, proj);
    k_flash<<<BZ * NCHUNK,  256, 0, stream>>>(src, proj, len, scores, part_ml, part_c);
    k_merge<<<BZ,           256, 0, stream>>>(part_ml, part_c, scores, len, c_ws, out + BZ * DIM);
    k_out  <<<DIM / 8,      256, 0, stream>>>(c_ws, tgt, Wo, out);
}

// Round 4
// 82.329 us; speedup vs baseline: 1.1366x; 1.1366x over previous
//
#include <hip/hip_runtime.h>
#include <math.h>

#define BZ 32
#define SRC_LEN 2048
#define DIM 1024
#define NCHUNK 64          // chunks per batch; chunk j owns rows s = j + 64*k

// ---- shared row-matvec core: wave owns 2 W-rows; act[32][1024] LDS-staged --
// acc{0,1}[b] = dot(Wrow{0,1}, act[b][:]) after butterfly reduce (all lanes).
__device__ __forceinline__ void rowmv(const float* __restrict__ Wrow0,
                                      const float* __restrict__ Wrow1,
                                      const float* __restrict__ act,
                                      float (*al)[260],
                                      float* acc0, float* acc1,
                                      int lane, int wave) {
#pragma unroll
    for (int i = 0; i < BZ; ++i) { acc0[i] = 0.f; acc1[i] = 0.f; }
    for (int ks = 0; ks < 4; ++ks) {
        __syncthreads();
        // stage act[:, ks*256 .. +256): wave w stages rows 8w..8w+7 (coalesced 1KB/instr)
#pragma unroll
        for (int j = 0; j < 8; ++j) {
            const int b = wave * 8 + j;
            *(float4*)&al[b][4 * lane] =
                *(const float4*)&act[b * DIM + ks * 256 + 4 * lane];
        }
        __syncthreads();
        const float4 w0 = *(const float4*)&Wrow0[ks * 256 + 4 * lane];
        const float4 w1 = *(const float4*)&Wrow1[ks * 256 + 4 * lane];
#pragma unroll
        for (int b = 0; b < BZ; ++b) {
            const float4 a = *(const float4*)&al[b][4 * lane];   // b128, rotated m134 pattern
            acc0[b] += w0.x * a.x + w0.y * a.y + w0.z * a.z + w0.w * a.w;
            acc1[b] += w1.x * a.x + w1.y * a.y + w1.z * a.z + w1.w * a.w;
        }
    }
#pragma unroll
    for (int b0 = 0; b0 < BZ; b0 += 2) {
#pragma unroll
        for (int off = 32; off > 0; off >>= 1) {
            acc0[b0 + 0] += __shfl_xor(acc0[b0 + 0], off, 64);
            acc0[b0 + 1] += __shfl_xor(acc0[b0 + 1], off, 64);
            acc1[b0 + 0] += __shfl_xor(acc1[b0 + 0], off, 64);
            acc1[b0 + 1] += __shfl_xor(acc1[b0 + 1], off, 64);
        }
    }
}

// ---- kernel A: proj = tgt@Wg^T  (rows 0..1023)  and  tpart = tgt@Wo_right^T
// grid 256 blocks x 256 thr; 8 W-rows per block. Wg+Wo_right read exactly once.
__global__ __launch_bounds__(256) void kA(const float* __restrict__ Wg,
                                          const float* __restrict__ Wo,
                                          const float* __restrict__ tgt,
                                          float* __restrict__ proj,
                                          float* __restrict__ tpart) {
    __shared__ float al[BZ][260];
    const int t = threadIdx.x, lane = t & 63, wave = t >> 6;
    const int r0 = blockIdx.x * 8 + wave * 2;
    const bool isWg = (r0 < DIM);
    const float* W0 = isWg ? &Wg[(size_t)r0 * DIM]
                           : &Wo[(size_t)(r0 - DIM) * (2 * DIM) + DIM];
    const float* W1 = isWg ? &Wg[(size_t)(r0 + 1) * DIM]
                           : &Wo[(size_t)(r0 + 1 - DIM) * (2 * DIM) + DIM];
    float acc0[BZ], acc1[BZ];
    rowmv(W0, W1, tgt, al, acc0, acc1, lane, wave);
    if (lane == 0) {
        if (isWg) {
#pragma unroll
            for (int b = 0; b < BZ; ++b) {
                proj[b * DIM + r0]     = acc0[b];
                proj[b * DIM + r0 + 1] = acc1[b];
            }
        } else {
#pragma unroll
            for (int b = 0; b < BZ; ++b) {
                tpart[b * DIM + (r0 - DIM)]     = acc0[b];
                tpart[b * DIM + (r0 - DIM) + 1] = acc1[b];
            }
        }
    }
}

// ---- kernel B: out = c@Wo_left^T + tpart. grid 128 blocks. -----------------
__global__ __launch_bounds__(256) void kB(const float* __restrict__ Wo,
                                          const float* __restrict__ c_ws,
                                          const float* __restrict__ tpart,
                                          float* __restrict__ outp) {
    __shared__ float al[BZ][260];
    const int t = threadIdx.x, lane = t & 63, wave = t >> 6;
    const int d0 = blockIdx.x * 8 + wave * 2;
    float acc0[BZ], acc1[BZ];
    rowmv(&Wo[(size_t)d0 * (2 * DIM)], &Wo[(size_t)(d0 + 1) * (2 * DIM)],
          c_ws, al, acc0, acc1, lane, wave);
    if (lane == 0) {
#pragma unroll
        for (int b = 0; b < BZ; ++b) {
            outp[b * DIM + d0]     = acc0[b] + tpart[b * DIM + d0];
            outp[b * DIM + d0 + 1] = acc1[b] + tpart[b * DIM + d0 + 1];
        }
    }
}

// ---------------- kernel 2: flash pass — UNCHANGED from R3 (control) --------
__global__ __launch_bounds__(256) void k_flash(const float* __restrict__ src,
                                               const float* __restrict__ proj,
                                               const int* __restrict__ lens,
                                               float* __restrict__ scores,
                                               float* __restrict__ part_ml,
                                               float* __restrict__ part_c) {
    const int blk = blockIdx.x;
    const int b = blk & 31;
    const int j = blk >> 5;
    const int lane = threadIdx.x & 63;
    const int wave = threadIdx.x >> 6;
    const int len = lens[b];

    int nk = 0;
    if (len > j) nk = (len - j + 63) >> 6;

    float4 pj[4];
#pragma unroll
    for (int q = 0; q < 4; ++q)
        pj[q] = *(const float4*)&proj[b * DIM + (q * 64 + lane) * 4];

    const float* sb = src + (size_t)b * SRC_LEN * DIM;
    float m = -INFINITY, l = 0.f;
    float c[16];
#pragma unroll
    for (int i = 0; i < 16; ++i) c[i] = 0.f;

    const int kbeg = wave * 8;
    const int kend = (kbeg + 8 < nk) ? (kbeg + 8) : nk;

    for (int k0 = kbeg; k0 < kend; k0 += 4) {
        const int nb = ((kend - k0) < 4) ? (kend - k0) : 4;
        float4 v[4][4];
        float sc[4];
#pragma unroll
        for (int r = 0; r < 4; ++r) {
            if (r < nb) {
                const int s = j + 64 * (k0 + r);
                const float* row = sb + (size_t)s * DIM;
                float d = 0.f;
#pragma unroll
                for (int q = 0; q < 4; ++q) {
                    v[r][q] = *(const float4*)&row[(q * 64 + lane) * 4];
                    d += v[r][q].x * pj[q].x + v[r][q].y * pj[q].y +
                         v[r][q].z * pj[q].z + v[r][q].w * pj[q].w;
                }
                sc[r] = d;
            } else {
                sc[r] = -INFINITY;
            }
        }
#pragma unroll
        for (int off = 32; off > 0; off >>= 1) {
            sc[0] += __shfl_xor(sc[0], off, 64);
            sc[1] += __shfl_xor(sc[1], off, 64);
            sc[2] += __shfl_xor(sc[2], off, 64);
            sc[3] += __shfl_xor(sc[3], off, 64);
        }
        if (lane == 0) {
#pragma unroll
            for (int r = 0; r < 4; ++r)
                if (r < nb) scores[b * SRC_LEN + j + 64 * (k0 + r)] = sc[r];
        }
        const float mn = fmaxf(m, fmaxf(fmaxf(sc[0], sc[1]), fmaxf(sc[2], sc[3])));
        const float scale = __expf(m - mn);
        float w[4];
#pragma unroll
        for (int r = 0; r < 4; ++r) w[r] = __expf(sc[r] - mn);
        l = l * scale + (w[0] + w[1] + w[2] + w[3]);
#pragma unroll
        for (int i = 0; i < 16; ++i) c[i] *= scale;
#pragma unroll
        for (int r = 0; r < 4; ++r) {
            if (r < nb) {
#pragma unroll
                for (int q = 0; q < 4; ++q) {
                    c[q * 4 + 0] += w[r] * v[r][q].x;
                    c[q * 4 + 1] += w[r] * v[r][q].y;
                    c[q * 4 + 2] += w[r] * v[r][q].z;
                    c[q * 4 + 3] += w[r] * v[r][q].w;
                }
            }
        }
        m = mn;
    }

    __shared__ float s_c[4][1024];
    __shared__ float s_ml[4][2];
#pragma unroll
    for (int q = 0; q < 4; ++q)
        *(float4*)&s_c[wave][(q * 64 + lane) * 4] =
            make_float4(c[q * 4 + 0], c[q * 4 + 1], c[q * 4 + 2], c[q * 4 + 3]);
    if (lane == 0) { s_ml[wave][0] = m; s_ml[wave][1] = l; }
    __syncthreads();

    const int t = threadIdx.x;
    float M = fmaxf(fmaxf(s_ml[0][0], s_ml[1][0]), fmaxf(s_ml[2][0], s_ml[3][0]));
    float L = 0.f;
    float4 acc = make_float4(0.f, 0.f, 0.f, 0.f);
#pragma unroll
    for (int wv = 0; wv < 4; ++wv) {
        const float mw = s_ml[wv][0];
        const float e = (mw == -INFINITY) ? 0.f : __expf(mw - M);
        L += e * s_ml[wv][1];
        float4 cv = *(const float4*)&s_c[wv][t * 4];
        acc.x += e * cv.x; acc.y += e * cv.y; acc.z += e * cv.z; acc.w += e * cv.w;
    }
    if (t == 0) { part_ml[2 * blk] = M; part_ml[2 * blk + 1] = L; }
    if (M > -INFINITY)
        *(float4*)&part_c[(size_t)blk * DIM + t * 4] = acc;
}

// ---------------- kernel 3: merge — 4x more parallel (128 blocks) -----------
// block = (b = blk&31, slice = blk>>5). c cols [slice*256,+256), align s [slice*512,+512).
__global__ __launch_bounds__(256) void k_merge(const float* __restrict__ part_ml,
                                               const float* __restrict__ part_c,
                                               const float* __restrict__ scores,
                                               const int* __restrict__ lens,
                                               float* __restrict__ c_ws,
                                               float* __restrict__ out_align) {
    __shared__ float s_m[NCHUNK], s_l[NCHUNK];
    const int b = blockIdx.x & 31;
    const int slice = blockIdx.x >> 5;
    const int t = threadIdx.x;
    if (t < NCHUNK) {
        s_m[t] = part_ml[2 * (t * BZ + b)];
        s_l[t] = part_ml[2 * (t * BZ + b) + 1];
    }
    __syncthreads();
    float M = -INFINITY;
#pragma unroll
    for (int i = 0; i < NCHUNK; ++i) M = fmaxf(M, s_m[i]);
    float L = 0.f;
#pragma unroll
    for (int i = 0; i < NCHUNK; ++i)
        if (s_m[i] > -INFINITY) L += __expf(s_m[i] - M) * s_l[i];
    const float invL = 1.f / L;

    const int col = slice * 256 + t;
    float acc = 0.f;
    for (int i = 0; i < NCHUNK; ++i) {
        if (s_m[i] > -INFINITY)
            acc += __expf(s_m[i] - M) * part_c[(size_t)(i * BZ + b) * DIM + col];
    }
    c_ws[b * DIM + col] = acc * invL;

    const int len = lens[b];
#pragma unroll
    for (int u = 0; u < 2; ++u) {
        const int s = slice * 512 + u * 256 + t;
        float a = 0.f;
        if (s < len) a = __expf(scores[b * SRC_LEN + s] - M) * invL;
        out_align[b * SRC_LEN + s] = a;
    }
}

extern "C" void kernel_launch(void* const* d_in, const int* in_sizes, int n_in,
                              void* d_out, int out_size, void* d_ws, size_t ws_size,
                              hipStream_t stream) {
    const float* src = (const float*)d_in[0];   // (32, 2048, 1024)
    const float* tgt = (const float*)d_in[1];   // (32, 1, 1024)
    const float* Wg  = (const float*)d_in[2];   // (1024, 1024)
    const float* Wo  = (const float*)d_in[3];   // (1024, 2048)
    const int*   len = (const int*)d_in[4];     // (32,)
    float* out = (float*)d_out;                 // attn_h [0,32768) ++ align

    float* ws = (float*)d_ws;
    float* proj    = ws;                               // 32*1024
    float* scores  = proj + BZ * DIM;                  // 32*2048
    float* part_ml = scores + BZ * SRC_LEN;            // 2048*2
    float* part_c  = part_ml + BZ * NCHUNK * 2;        // 2048*1024 (8 MB)
    float* c_ws    = part_c + (size_t)BZ * NCHUNK * DIM;   // 32*1024
    float* tpart   = c_ws + BZ * DIM;                  // 32*1024

    kA     <<<256,          256, 0, stream>>>(Wg, Wo, tgt, proj, tpart);
    k_flash<<<BZ * NCHUNK,  256, 0, stream>>>(src, proj, len, scores, part_ml, part_c);
    k_merge<<<128,          256, 0, stream>>>(part_ml, part_c, scores, len, c_ws, out + BZ * DIM);
    kB     <<<128,          256, 0, stream>>>(Wo, c_ws, tpart, out);
}